// Round 5
// baseline (408.554 us; speedup 1.0000x reference)
//
#include <hip/hip_runtime.h>
#include <hip/hip_bf16.h>

// Problem constants
#define H_ 128
#define W_ 128
#define HW 16384          // H*W
#define CIN 64
#define COUT 128
#define KK9 9
#define BATCH 8
#define NPIX (BATCH * HW) // 131072
#define KDIM 576          // CIN*KK9
#define APITCH 584        // ldsA row pitch in bf16 elems (576 + 8)

typedef short bf16x8 __attribute__((ext_vector_type(8)));
typedef float f32x4  __attribute__((ext_vector_type(4)));
typedef unsigned short ushort_t;

__device__ __forceinline__ float us2f(unsigned short u) {
    unsigned int v = ((unsigned int)u) << 16;
    float f;
    __builtin_memcpy(&f, &v, 4);
    return f;
}
__device__ __forceinline__ unsigned short f2us_bf(float f) {
    __hip_bfloat16 h = __float2bfloat16(f);
    unsigned short u;
    __builtin_memcpy(&u, &h, 2);
    return u;
}
__device__ __forceinline__ unsigned int pack2(float a, float b) {
    return (unsigned int)f2us_bf(a) | ((unsigned int)f2us_bf(b) << 16);
}

template <bool F32>
__device__ __forceinline__ float ld_in(const void* p, long i) {
    if (F32) return ((const float*)p)[i];
    return us2f(((const unsigned short*)p)[i]);
}

// ---------------------------------------------------------------------------
// detect_dtype: inputs f32 (flag=1) vs bf16 (flag=0).
// ---------------------------------------------------------------------------
__global__ void detect_dtype(const unsigned short* __restrict__ xr,
                             float* __restrict__ flag) {
    int big = 0;
    for (int i = 0; i < 512; ++i) {
        int ex = (xr[i] >> 7) & 0xFF;
        big += (ex >= 0xC0);
    }
    flag[0] = big ? 1.0f : 0.0f;
}

// ---------------------------------------------------------------------------
// prep_weights: bf16 MFMA weight layouts + f32 bias.
// wTb  [128 co][576 k] bf16, k = kk*64+ci   (conv W^T)
// wcatb[32 co2][576 k] bf16 (rows 0..17 offset_w, 18..26 mask_w, rest 0)
// bias [32] f32
// ---------------------------------------------------------------------------
template <bool F32>
__global__ void prep_weights(const void* __restrict__ offw,
                             const void* __restrict__ offb,
                             const void* __restrict__ maskw,
                             const void* __restrict__ maskb,
                             const void* __restrict__ convw,
                             const float* __restrict__ flag,
                             ushort_t* __restrict__ wTb,
                             ushort_t* __restrict__ wcatb,
                             float* __restrict__ bias) {
    if ((flag[0] != 0.0f) != F32) return;
    int i = blockIdx.x * 256 + threadIdx.x;
    if (i < 73728) {
        int co = i / KDIM, k = i - co * KDIM;
        int kk = k >> 6, ci = k & 63;
        wTb[i] = f2us_bf(ld_in<F32>(convw, (long)co * KDIM + ci * 9 + kk));
    } else if (i < 73728 + 18432) {
        int j = i - 73728;
        int co2 = j / KDIM, k = j - co2 * KDIM;
        int kk = k >> 6, ci = k & 63;
        float v = 0.0f;
        if (co2 < 18)      v = ld_in<F32>(offw,  (long)co2 * KDIM + ci * 9 + kk);
        else if (co2 < 27) v = ld_in<F32>(maskw, (long)(co2 - 18) * KDIM + ci * 9 + kk);
        wcatb[j] = f2us_bf(v);
    } else if (i < 73728 + 18432 + 32) {
        int j = i - 73728 - 18432;
        float v = 0.0f;
        if (j < 18)      v = ld_in<F32>(offb, j);
        else if (j < 27) v = ld_in<F32>(maskb, j - 18);
        bias[j] = v;
    }
}

// ---------------------------------------------------------------------------
// transpose_x: raw x NCHW -> NHWC bf16 (halves gather traffic downstream).
// ---------------------------------------------------------------------------
template <bool F32>
__global__ __launch_bounds__(256) void transpose_x(const void* __restrict__ x,
                                                   const float* __restrict__ flag,
                                                   ushort_t* __restrict__ xnb) {
    if ((flag[0] != 0.0f) != F32) return;
    __shared__ float tile[CIN][64 + 1];
    int blk  = blockIdx.x;
    int b    = blk >> 8;
    int pix0 = (blk & 255) * 64;
    int t    = threadIdx.x;
    int lane = t & 63;
    int grp  = t >> 6;
#pragma unroll
    for (int r = 0; r < 16; ++r) {
        int ci = r * 4 + grp;
        tile[ci][lane] = ld_in<F32>(x, (long)(b * CIN + ci) * HW + pix0 + lane);
    }
    __syncthreads();
#pragma unroll
    for (int r = 0; r < 16; ++r) {
        int px = r * 4 + grp;
        xnb[(size_t)(b * HW + pix0 + px) * CIN + lane] = f2us_bf(tile[lane][px]);
    }
}

// ---------------------------------------------------------------------------
// conv_offmask_mfma: implicit-GEMM 3x3 conv -> 27 ch via MFMA.
// Block = 64 px x 32 co. Phase 1: copy full [64 px][576 k] window into LDS
// (pure bf16 copy, all 9 taps, deep MLP). One barrier. Phase 2: 18 k-steps,
// B-fragments streamed from global (L2-resident, 36 KB).
// ---------------------------------------------------------------------------
__global__ __launch_bounds__(256) void conv_offmask_mfma(
        const ushort_t* __restrict__ xnb,
        const ushort_t* __restrict__ wcatb,
        const float* __restrict__ bias,
        float* __restrict__ off_ws,
        float* __restrict__ mask_ws) {
    __shared__ ushort_t ldsA[64 * APITCH];

    int t    = threadIdx.x;
    int pix0 = blockIdx.x * 64;
    int b    = pix0 >> 14;
    int rem0 = pix0 & 16383;
    int y    = rem0 >> 7;
    int x0   = rem0 & 127;

    // phase 1: thread = (pixel sp, channel-quarter cq)
    {
        int sp = t >> 2;
        int cq = t & 3;
        int xx = x0 + sp;
        const ushort_t* xb = xnb + (size_t)b * HW * CIN + cq * 16;
        ushort_t* dst0 = ldsA + sp * APITCH + cq * 16;
#pragma unroll
        for (int kk = 0; kk < KK9; ++kk) {
            int yy = y + kk / 3 - 1;
            int xq = xx + kk % 3 - 1;
            uint4 r0 = make_uint4(0, 0, 0, 0), r1 = make_uint4(0, 0, 0, 0);
            if (yy >= 0 && yy < H_ && xq >= 0 && xq < W_) {
                const ushort_t* src = xb + (size_t)(yy * W_ + xq) * CIN;
                r0 = *(const uint4*)src;
                r1 = *(const uint4*)(src + 8);
            }
            *(uint4*)(dst0 + kk * 64)     = r0;
            *(uint4*)(dst0 + kk * 64 + 8) = r1;
        }
    }
    __syncthreads();

    // phase 2: MFMA, 2 n-tiles of 16 co
    int wave = t >> 6;
    int lane = t & 63;
    int mrow = lane & 15;
    int quad = lane >> 4;
    f32x4 acc[2];
    acc[0] = (f32x4){0.f, 0.f, 0.f, 0.f};
    acc[1] = (f32x4){0.f, 0.f, 0.f, 0.f};
    const ushort_t* arow = ldsA + (wave * 16 + mrow) * APITCH + quad * 8;
    const ushort_t* wp   = wcatb + mrow * KDIM + quad * 8;
#pragma unroll 3
    for (int ks = 0; ks < 18; ++ks) {
        bf16x8 af = *(const bf16x8*)(arow + ks * 32);
        bf16x8 b0 = *(const bf16x8*)(wp + ks * 32);
        bf16x8 b1 = *(const bf16x8*)(wp + 16 * KDIM + ks * 32);
        acc[0] = __builtin_amdgcn_mfma_f32_16x16x32_bf16(af, b0, acc[0], 0, 0, 0);
        acc[1] = __builtin_amdgcn_mfma_f32_16x16x32_bf16(af, b1, acc[1], 0, 0, 0);
    }

    // epilogue
#pragma unroll
    for (int n = 0; n < 2; ++n) {
        int co2 = n * 16 + mrow;
        if (co2 >= 27) continue;
        float bs = bias[co2];
#pragma unroll
        for (int r = 0; r < 4; ++r) {
            int px = wave * 16 + quad * 4 + r;
            float v = acc[n][r] + bs;
            if (co2 < 18) {
                off_ws[(size_t)(b * 18 + co2) * HW + rem0 + px] = v;
            } else {
                mask_ws[(size_t)(b * 9 + (co2 - 18)) * HW + rem0 + px] =
                    1.0f / (1.0f + __expf(-v));
            }
        }
    }
}

// ---------------------------------------------------------------------------
// deform_mfma: fused bilinear sampling + GEMM.
// Block = 64 px x 128 co. Phase 1: sample ALL 9 taps into ldsA[64][576]
// (36 independent corner loads per thread -> deep MLP). ONE barrier.
// Phase 2: 18 k-steps x 8 n-tiles; B-fragments streamed from global
// (W^T 147 KB, L2-resident). Output f32 NCHW pre-BN + BN stats.
// ---------------------------------------------------------------------------
__global__ __launch_bounds__(256) void deform_mfma(
        const ushort_t* __restrict__ xnb,
        const float* __restrict__ off_ws,
        const float* __restrict__ mask_ws,
        const ushort_t* __restrict__ wTb,
        float* __restrict__ out,
        float* __restrict__ gstat) {
    __shared__ ushort_t ldsA[64 * APITCH];

    int t    = threadIdx.x;
    int pix0 = blockIdx.x * 64;
    int b    = pix0 >> 14;
    int rem0 = pix0 & 16383;
    int y    = rem0 >> 7;
    int x0   = rem0 & 127;

    // ---- phase 1: sampling (thread = pixel sp x 16 channels cq) ----
    {
        int sp = t >> 2;
        int cq = t & 3;
        int xx = x0 + sp;
        const ushort_t* xb  = xnb + (size_t)b * HW * CIN + cq * 16;
        const float* offp   = off_ws  + (size_t)b * 18 * HW + y * W_ + xx;
        const float* maskp  = mask_ws + (size_t)b * 9  * HW + y * W_ + xx;
        ushort_t* dst0 = ldsA + sp * APITCH + cq * 16;
#pragma unroll 3
        for (int kk = 0; kk < KK9; ++kk) {
            float offy = offp[(2 * kk) * HW];
            float offx = offp[(2 * kk + 1) * HW];
            float m    = maskp[kk * HW];
            float py = (float)(y + kk / 3 - 1) + offy;
            float px = (float)(xx + kk % 3 - 1) + offx;
            float y0f = floorf(py), x0f = floorf(px);
            int yi = (int)y0f, xi = (int)x0f;
            float wy1 = py - y0f, wx1 = px - x0f;
            float wy0 = 1.0f - wy1, wx0 = 1.0f - wx1;
            float v[16];
#pragma unroll
            for (int j = 0; j < 16; ++j) v[j] = 0.0f;
#pragma unroll
            for (int c = 0; c < 4; ++c) {
                int ys = yi + (c >> 1);
                int xs = xi + (c & 1);
                float wgt = ((c >> 1) ? wy1 : wy0) * ((c & 1) ? wx1 : wx0);
                if (ys >= 0 && ys < H_ && xs >= 0 && xs < W_) {
                    const ushort_t* src = xb + (size_t)(ys * W_ + xs) * CIN;
                    uint4 r0 = *(const uint4*)src;
                    uint4 r1 = *(const uint4*)(src + 8);
                    unsigned int ww[8] = {r0.x, r0.y, r0.z, r0.w,
                                          r1.x, r1.y, r1.z, r1.w};
#pragma unroll
                    for (int j = 0; j < 8; ++j) {
                        v[2 * j]     = fmaf(wgt, us2f((ushort_t)(ww[j] & 0xffffu)), v[2 * j]);
                        v[2 * j + 1] = fmaf(wgt, us2f((ushort_t)(ww[j] >> 16)),     v[2 * j + 1]);
                    }
                }
            }
            unsigned int w[8];
#pragma unroll
            for (int j = 0; j < 8; ++j)
                w[j] = pack2(v[2 * j] * m, v[2 * j + 1] * m);
            *(uint4*)(dst0 + kk * 64)     = make_uint4(w[0], w[1], w[2], w[3]);
            *(uint4*)(dst0 + kk * 64 + 8) = make_uint4(w[4], w[5], w[6], w[7]);
        }
    }
    __syncthreads();

    // ---- phase 2: MFMA, 8 n-tiles, B from global ----
    int wave = t >> 6;
    int lane = t & 63;
    int mrow = lane & 15;
    int quad = lane >> 4;
    f32x4 acc[8];
#pragma unroll
    for (int n = 0; n < 8; ++n) acc[n] = (f32x4){0.f, 0.f, 0.f, 0.f};
    const ushort_t* arow = ldsA + (wave * 16 + mrow) * APITCH + quad * 8;
    const ushort_t* wp   = wTb + mrow * KDIM + quad * 8;
#pragma unroll 2
    for (int ks = 0; ks < 18; ++ks) {
        bf16x8 bfr[8];
#pragma unroll
        for (int n = 0; n < 8; ++n)
            bfr[n] = *(const bf16x8*)(wp + n * 16 * KDIM + ks * 32);
        bf16x8 af = *(const bf16x8*)(arow + ks * 32);
#pragma unroll
        for (int n = 0; n < 8; ++n)
            acc[n] = __builtin_amdgcn_mfma_f32_16x16x32_bf16(af, bfr[n], acc[n], 0, 0, 0);
    }

    // ---- epilogue: store f32 NCHW + BN stats (reuse ldsA as scratch) ----
    __syncthreads();                       // all ldsA reads complete
    float* red = (float*)ldsA;
    red[t] = 0.0f;
    __syncthreads();
    float* ob = out + (size_t)b * COUT * HW + rem0;
#pragma unroll
    for (int n = 0; n < 8; ++n) {
        int co = n * 16 + mrow;
        float s = 0.f, ss = 0.f;
#pragma unroll
        for (int r = 0; r < 4; ++r) {
            int px = wave * 16 + quad * 4 + r;
            float v = acc[n][r];
            ob[(size_t)co * HW + px] = v;
            s += v;
            ss += v * v;
        }
        atomicAdd(&red[co], s);
        atomicAdd(&red[128 + co], ss);
    }
    __syncthreads();
    atomicAdd(&gstat[(blockIdx.x & 15) * 256 + t], red[t]);
}

// ---------------------------------------------------------------------------
// bn_stats: fold 16 partial copies -> mean / rstd (NaN-guarded).
// ---------------------------------------------------------------------------
__global__ void bn_stats(const float* __restrict__ gstat, float* __restrict__ mv) {
    int co = threadIdx.x;  // 128 threads
    float s = 0.f, ss = 0.f;
#pragma unroll
    for (int part = 0; part < 16; ++part) {
        s  += gstat[part * 256 + co];
        ss += gstat[part * 256 + 128 + co];
    }
    const float invN = 1.0f / (float)NPIX;
    float mean = s * invN;
    float var  = ss * invN - mean * mean;
    if (!isfinite(mean)) mean = 0.0f;
    float r = rsqrtf(fmaxf(var, 0.0f) + 1e-5f);
    if (!isfinite(r)) r = 1.0f;
    mv[co]       = mean;
    mv[128 + co] = r;
}

// ---------------------------------------------------------------------------
// bn_apply: in-place normalize + ReLU on d_out (f32 NCHW), float4/thread.
// ---------------------------------------------------------------------------
__global__ __launch_bounds__(256) void bn_apply(float* __restrict__ out,
                                                const float* __restrict__ mv) {
    int gid = blockIdx.x * 256 + threadIdx.x;
    size_t i4 = (size_t)gid * 4;
    int co = ((int)(i4 >> 14)) & 127;
    float mean = mv[co], rstd = mv[128 + co];
    float4* p = (float4*)(out + i4);
    float4 v = *p;
    v.x = fmaxf((v.x - mean) * rstd, 0.0f);
    v.y = fmaxf((v.y - mean) * rstd, 0.0f);
    v.z = fmaxf((v.z - mean) * rstd, 0.0f);
    v.w = fmaxf((v.w - mean) * rstd, 0.0f);
    *p = v;
}

// ---------------------------------------------------------------------------
extern "C" void kernel_launch(void* const* d_in, const int* in_sizes, int n_in,
                              void* d_out, int out_size, void* d_ws, size_t ws_size,
                              hipStream_t stream) {
    (void)in_sizes; (void)n_in; (void)out_size; (void)ws_size;
    const void* x     = d_in[0];
    const void* offw  = d_in[1];
    const void* offb  = d_in[2];
    const void* maskw = d_in[3];
    const void* maskb = d_in[4];
    const void* convw = d_in[5];

    float* ws       = (float*)d_ws;
    float* off_ws   = ws;                      // 2,359,296 f32
    float* mask_ws  = off_ws + 2359296;        // 1,179,648 f32
    float* bias     = mask_ws + 1179648;       //        32 f32
    float* gstat    = bias + 32;               //     4,096 f32
    float* mv       = gstat + 4096;            //       256 f32
    float* flag     = mv + 256;                //        16 f32
    ushort_t* wTb   = (ushort_t*)(flag + 16);  //    73,728 bf16
    ushort_t* wcatb = wTb + 73728;             //    18,432 bf16
    ushort_t* xnb   = wcatb + 18432;           // 8,388,608 bf16 (NHWC x)
    float* out      = (float*)d_out;

    hipMemsetAsync(gstat, 0, 4096 * sizeof(float), stream);
    detect_dtype<<<1, 1, 0, stream>>>((const unsigned short*)x, flag);
    prep_weights<true><<<361, 256, 0, stream>>>(offw, offb, maskw, maskb, convw, flag, wTb, wcatb, bias);
    prep_weights<false><<<361, 256, 0, stream>>>(offw, offb, maskw, maskb, convw, flag, wTb, wcatb, bias);
    transpose_x<true><<<2048, 256, 0, stream>>>(x, flag, xnb);
    transpose_x<false><<<2048, 256, 0, stream>>>(x, flag, xnb);
    conv_offmask_mfma<<<2048, 256, 0, stream>>>(xnb, wcatb, bias, off_ws, mask_ws);
    deform_mfma<<<2048, 256, 0, stream>>>(xnb, off_ws, mask_ws, wTb, out, gstat);
    bn_stats<<<1, 128, 0, stream>>>(gstat, mv);
    bn_apply<<<16384, 256, 0, stream>>>(out, mv);
}

// Round 6
// 266.455 us; speedup vs baseline: 1.5333x; 1.5333x over previous
//
#include <hip/hip_runtime.h>
#include <hip/hip_bf16.h>

// Problem constants
#define H_ 128
#define W_ 128
#define HW 16384          // H*W
#define CIN 64
#define COUT 128
#define KK9 9
#define BATCH 8
#define NPIX (BATCH * HW) // 131072
#define KDIM 576          // CIN*KK9

typedef short bf16x8 __attribute__((ext_vector_type(8)));
typedef float f32x4  __attribute__((ext_vector_type(4)));
typedef unsigned short ushort_t;

union U4B { uint4 u; bf16x8 v; };

__device__ __forceinline__ float us2f(unsigned short u) {
    unsigned int v = ((unsigned int)u) << 16;
    float f;
    __builtin_memcpy(&f, &v, 4);
    return f;
}
__device__ __forceinline__ float lo_f(unsigned int w) {   // low bf16 of dword
    unsigned int v = w << 16;
    float f;
    __builtin_memcpy(&f, &v, 4);
    return f;
}
__device__ __forceinline__ float hi_f(unsigned int w) {   // high bf16 of dword
    unsigned int v = w & 0xffff0000u;
    float f;
    __builtin_memcpy(&f, &v, 4);
    return f;
}
__device__ __forceinline__ unsigned short f2us_bf(float f) {
    __hip_bfloat16 h = __float2bfloat16(f);
    unsigned short u;
    __builtin_memcpy(&u, &h, 2);
    return u;
}
__device__ __forceinline__ unsigned int pack2(float a, float b) {
    return (unsigned int)f2us_bf(a) | ((unsigned int)f2us_bf(b) << 16);
}

template <bool F32>
__device__ __forceinline__ float ld_in(const void* p, long i) {
    if (F32) return ((const float*)p)[i];
    return us2f(((const unsigned short*)p)[i]);
}

// ---------------------------------------------------------------------------
// detect_dtype: inputs f32 (flag=1) vs bf16 (flag=0).
// ---------------------------------------------------------------------------
__global__ void detect_dtype(const unsigned short* __restrict__ xr,
                             float* __restrict__ flag) {
    int big = 0;
    for (int i = 0; i < 512; ++i) {
        int ex = (xr[i] >> 7) & 0xFF;
        big += (ex >= 0xC0);
    }
    flag[0] = big ? 1.0f : 0.0f;
}

// ---------------------------------------------------------------------------
// prep_weights: weights in MFMA-FRAGMENT-LINEAR order (zero-conflict LDS /
// fully-coalesced loads downstream).
// wTs  [18 ks][8 n][64 lane][8 j] bf16: element = conv B[co=n*16+(lane&15)]
//      [k=ks*32+(lane>>4)*8+j], k=kk*64+ci, from conv_w[co][ci][kk].
// wcats[18 ks][2 n][64 lane][8 j]: rows 0..17 offset_w, 18..26 mask_w, rest 0.
// bias [32] f32.
// ---------------------------------------------------------------------------
template <bool F32>
__global__ void prep_weights(const void* __restrict__ offw,
                             const void* __restrict__ offb,
                             const void* __restrict__ maskw,
                             const void* __restrict__ maskb,
                             const void* __restrict__ convw,
                             const float* __restrict__ flag,
                             ushort_t* __restrict__ wTs,
                             ushort_t* __restrict__ wcats,
                             float* __restrict__ bias) {
    if ((flag[0] != 0.0f) != F32) return;
    int i = blockIdx.x * 256 + threadIdx.x;
    if (i < 73728) {
        int j = i & 7, lane = (i >> 3) & 63, n = (i >> 9) & 7, ks = i >> 12;
        int co = n * 16 + (lane & 15);
        int k  = ks * 32 + ((lane >> 4) << 3) + j;
        int kk = k >> 6, ci = k & 63;
        wTs[i] = f2us_bf(ld_in<F32>(convw, (long)co * KDIM + ci * 9 + kk));
    } else if (i < 73728 + 18432) {
        int i2 = i - 73728;
        int j = i2 & 7, lane = (i2 >> 3) & 63, n = (i2 >> 9) & 1, ks = i2 >> 10;
        int co2 = n * 16 + (lane & 15);
        int k   = ks * 32 + ((lane >> 4) << 3) + j;
        int kk = k >> 6, ci = k & 63;
        float v = 0.0f;
        if (co2 < 18)      v = ld_in<F32>(offw,  (long)co2 * KDIM + ci * 9 + kk);
        else if (co2 < 27) v = ld_in<F32>(maskw, (long)(co2 - 18) * KDIM + ci * 9 + kk);
        wcats[i2] = f2us_bf(v);
    } else if (i < 73728 + 18432 + 32) {
        int j = i - 73728 - 18432;
        float v = 0.0f;
        if (j < 18)      v = ld_in<F32>(offb, j);
        else if (j < 27) v = ld_in<F32>(maskb, j - 18);
        bias[j] = v;
    }
}

// ---------------------------------------------------------------------------
// transpose_x: raw x NCHW -> NHWC bf16.
// ---------------------------------------------------------------------------
template <bool F32>
__global__ __launch_bounds__(256) void transpose_x(const void* __restrict__ x,
                                                   const float* __restrict__ flag,
                                                   ushort_t* __restrict__ xnb) {
    if ((flag[0] != 0.0f) != F32) return;
    __shared__ float tile[CIN][64 + 1];
    int blk  = blockIdx.x;
    int b    = blk >> 8;
    int pix0 = (blk & 255) * 64;
    int t    = threadIdx.x;
    int lane = t & 63;
    int grp  = t >> 6;
#pragma unroll
    for (int r = 0; r < 16; ++r) {
        int ci = r * 4 + grp;
        tile[ci][lane] = ld_in<F32>(x, (long)(b * CIN + ci) * HW + pix0 + lane);
    }
    __syncthreads();
#pragma unroll
    for (int r = 0; r < 16; ++r) {
        int px = r * 4 + grp;
        xnb[(size_t)(b * HW + pix0 + px) * CIN + lane] = f2us_bf(tile[lane][px]);
    }
}

// ---------------------------------------------------------------------------
// conv_mfma: implicit-GEMM 3x3 conv -> 27 ch. 512 thr / 128 px / 8 waves.
// A = raw bf16 window copies straight into MFMA A-fragments (registers),
// B = wcats staged once into LDS (fragment-linear). ONE barrier.
// Offsets written interleaved as (y,x) float2 pairs; mask sigmoid planes.
// ---------------------------------------------------------------------------
__global__ __launch_bounds__(512, 4) void conv_mfma(
        const ushort_t* __restrict__ xnb,
        const ushort_t* __restrict__ wcats,
        const float* __restrict__ bias,
        float* __restrict__ off2,
        float* __restrict__ mask_ws) {
    __shared__ uint4 ldsB4[2304];    // 36,864 B

    int t    = threadIdx.x;
    int pix0 = blockIdx.x * 128;
    int b    = pix0 >> 14;
    int rem0 = pix0 & 16383;
    int y    = rem0 >> 7;
    int x0   = rem0 & 127;

    // stage B (coalesced, once)
    const uint4* ws4 = (const uint4*)wcats;
#pragma unroll
    for (int i = t; i < 2304; i += 512) ldsB4[i] = ws4[i];

    int wave = t >> 6, lane = t & 63, mrow = lane & 15, quad = lane >> 4;
    int px_l = wave * 16 + mrow;
    int xx   = x0 + px_l;
    const ushort_t* xb = xnb + (size_t)b * HW * CIN;

    // A-fragments: raw copies of the shifted window
    uint4 af0[9], af1[9];
#pragma unroll
    for (int kk = 0; kk < 9; ++kk) {
        int yy = y + kk / 3 - 1;
        int xq = xx + kk % 3 - 1;
        bool ok = (yy >= 0) && (yy < H_) && (xq >= 0) && (xq < W_);
        const ushort_t* src = xb + (size_t)(yy * W_ + xq) * CIN + quad * 8;
        af0[kk] = ok ? *(const uint4*)src        : make_uint4(0, 0, 0, 0);
        af1[kk] = ok ? *(const uint4*)(src + 32) : make_uint4(0, 0, 0, 0);
    }
    __syncthreads();

    f32x4 acc[2];
    acc[0] = (f32x4){0.f, 0.f, 0.f, 0.f};
    acc[1] = (f32x4){0.f, 0.f, 0.f, 0.f};
    const ushort_t* ldsB = (const ushort_t*)ldsB4;
#pragma unroll
    for (int kk = 0; kk < 9; ++kk) {
#pragma unroll
        for (int half = 0; half < 2; ++half) {
            int ks = kk * 2 + half;
            U4B a; a.u = half ? af1[kk] : af0[kk];
#pragma unroll
            for (int n = 0; n < 2; ++n) {
                bf16x8 bf = *(const bf16x8*)(ldsB + ((ks * 2 + n) * 64 + lane) * 8);
                acc[n] = __builtin_amdgcn_mfma_f32_16x16x32_bf16(a.v, bf, acc[n], 0, 0, 0);
            }
        }
    }

    // epilogue
#pragma unroll
    for (int n = 0; n < 2; ++n) {
        int co2 = n * 16 + mrow;
        if (co2 >= 27) continue;
        float bs = bias[co2];
#pragma unroll
        for (int r = 0; r < 4; ++r) {
            int px = wave * 16 + quad * 4 + r;
            float v = acc[n][r] + bs;
            if (co2 < 18) {
                off2[((size_t)(b * 9 + (co2 >> 1)) * HW + rem0 + px) * 2 + (co2 & 1)] = v;
            } else {
                mask_ws[(size_t)(b * 9 + (co2 - 18)) * HW + rem0 + px] =
                    1.0f / (1.0f + __expf(-v));
            }
        }
    }
}

// ---------------------------------------------------------------------------
// deform_mfma: fused bilinear sampling + GEMM. 512 thr / 128 px / 8 waves.
// A-fragments sampled DIRECTLY into registers in MFMA layout (no LDS for A).
// B = full W^T (147 KB, fragment-linear) staged once into LDS. ONE barrier.
// Pre-BN output bf16 NHWC + per-channel BN stats.
// ---------------------------------------------------------------------------
__global__ __launch_bounds__(512, 2) void deform_mfma(
        const ushort_t* __restrict__ xnb,
        const float* __restrict__ off2,
        const float* __restrict__ mask_ws,
        const ushort_t* __restrict__ wTs,
        ushort_t* __restrict__ prebn,
        float* __restrict__ gstat) {
    __shared__ uint4 ldsB4[9216];    // 147,456 B
    __shared__ float red[256];

    int t    = threadIdx.x;
    int pix0 = blockIdx.x * 128;
    int b    = pix0 >> 14;
    int rem0 = pix0 & 16383;
    int y    = rem0 >> 7;
    int x0   = rem0 & 127;

    // stage B (coalesced, once per block; L2-resident source)
    const uint4* ws4 = (const uint4*)wTs;
#pragma unroll
    for (int i = 0; i < 18; ++i) ldsB4[i * 512 + t] = ws4[i * 512 + t];
    if (t < 256) red[t] = 0.0f;

    int wave = t >> 6, lane = t & 63, mrow = lane & 15, quad = lane >> 4;
    int px_l = wave * 16 + mrow;
    int xx   = x0 + px_l;
    const ushort_t* xb = xnb + (size_t)b * HW * CIN;
    size_t obase = (size_t)b * 9 * HW + y * W_ + xx;

    // ---- sample all 9 taps into register A-fragments ----
    uint4 af0[9], af1[9];
#pragma unroll
    for (int kk = 0; kk < 9; ++kk) {
        float2 off = *(const float2*)(off2 + (obase + (size_t)kk * HW) * 2);
        float m    = mask_ws[obase + (size_t)kk * HW];
        float py  = (float)(y + kk / 3 - 1) + off.x;
        float pxf = (float)(xx + kk % 3 - 1) + off.y;
        float y0f = floorf(py), x0f = floorf(pxf);
        int yi = (int)y0f, xi = (int)x0f;
        float wy1 = py - y0f, wx1 = pxf - x0f;
        float wy0 = 1.0f - wy1, wx0 = 1.0f - wx1;
        float v[16];
#pragma unroll
        for (int j = 0; j < 16; ++j) v[j] = 0.0f;
#pragma unroll
        for (int c = 0; c < 4; ++c) {
            int ys = yi + (c >> 1);
            int xs = xi + (c & 1);
            float wgt = ((c >> 1) ? wy1 : wy0) * ((c & 1) ? wx1 : wx0);
            if (ys >= 0 && ys < H_ && xs >= 0 && xs < W_) {
                const ushort_t* src = xb + (size_t)(ys * W_ + xs) * CIN + quad * 8;
                uint4 l4 = *(const uint4*)src;          // ci = quad*8..+8
                uint4 h4 = *(const uint4*)(src + 32);   // ci = 32+quad*8..+8
                unsigned int ww[8] = {l4.x, l4.y, l4.z, l4.w,
                                      h4.x, h4.y, h4.z, h4.w};
#pragma unroll
                for (int j = 0; j < 8; ++j) {
                    v[2 * j]     = fmaf(wgt, lo_f(ww[j]), v[2 * j]);
                    v[2 * j + 1] = fmaf(wgt, hi_f(ww[j]), v[2 * j + 1]);
                }
            }
        }
        unsigned int w[8];
#pragma unroll
        for (int j = 0; j < 8; ++j)
            w[j] = pack2(v[2 * j] * m, v[2 * j + 1] * m);
        af0[kk] = make_uint4(w[0], w[1], w[2], w[3]);
        af1[kk] = make_uint4(w[4], w[5], w[6], w[7]);
    }
    __syncthreads();

    // ---- MFMA: 18 k-steps x 8 n-tiles, B via conflict-free ds_read ----
    f32x4 acc[8];
#pragma unroll
    for (int n = 0; n < 8; ++n) acc[n] = (f32x4){0.f, 0.f, 0.f, 0.f};
    const ushort_t* ldsB = (const ushort_t*)ldsB4;
#pragma unroll
    for (int kk = 0; kk < 9; ++kk) {
#pragma unroll
        for (int half = 0; half < 2; ++half) {
            int ks = kk * 2 + half;
            U4B a; a.u = half ? af1[kk] : af0[kk];
#pragma unroll
            for (int n = 0; n < 8; ++n) {
                bf16x8 bf = *(const bf16x8*)(ldsB + ((ks * 8 + n) * 64 + lane) * 8);
                acc[n] = __builtin_amdgcn_mfma_f32_16x16x32_bf16(a.v, bf, acc[n], 0, 0, 0);
            }
        }
    }

    // ---- epilogue: bf16 NHWC store + BN stats (shuffle-reduce) ----
#pragma unroll
    for (int n = 0; n < 8; ++n) {
        int co = n * 16 + mrow;
        float s = 0.f, ss = 0.f;
#pragma unroll
        for (int r = 0; r < 4; ++r) {
            int pg = pix0 + wave * 16 + quad * 4 + r;
            float v = acc[n][r];
            prebn[(size_t)pg * COUT + co] = f2us_bf(v);
            s += v;
            ss += v * v;
        }
        s  += __shfl_xor(s, 16, 64);
        s  += __shfl_xor(s, 32, 64);
        ss += __shfl_xor(ss, 16, 64);
        ss += __shfl_xor(ss, 32, 64);
        if (quad == 0) {
            atomicAdd(&red[co], s);
            atomicAdd(&red[128 + co], ss);
        }
    }
    __syncthreads();
    if (t < 256) atomicAdd(&gstat[(blockIdx.x & 15) * 256 + t], red[t]);
}

// ---------------------------------------------------------------------------
// bn_stats: fold 16 partial copies -> mean / rstd (NaN-guarded).
// ---------------------------------------------------------------------------
__global__ void bn_stats(const float* __restrict__ gstat, float* __restrict__ mv) {
    int co = threadIdx.x;  // 128 threads
    float s = 0.f, ss = 0.f;
#pragma unroll
    for (int part = 0; part < 16; ++part) {
        s  += gstat[part * 256 + co];
        ss += gstat[part * 256 + 128 + co];
    }
    const float invN = 1.0f / (float)NPIX;
    float mean = s * invN;
    float var  = ss * invN - mean * mean;
    if (!isfinite(mean)) mean = 0.0f;
    float r = rsqrtf(fmaxf(var, 0.0f) + 1e-5f);
    if (!isfinite(r)) r = 1.0f;
    mv[co]       = mean;
    mv[128 + co] = r;
}

// ---------------------------------------------------------------------------
// bn_apply_t: read pre-BN bf16 NHWC, normalize+ReLU, write f32 NCHW d_out.
// Block = 64 px x 128 co via LDS transpose tile. Both sides coalesced.
// ---------------------------------------------------------------------------
__global__ __launch_bounds__(256) void bn_apply_t(const ushort_t* __restrict__ prebn,
                                                  const float* __restrict__ mv,
                                                  float* __restrict__ out) {
    __shared__ float tile[128 * 65];
    __shared__ float mvs[256];
    int t = threadIdx.x;
    mvs[t] = mv[t];
    __syncthreads();
    int pix0 = blockIdx.x * 64;
    int b    = pix0 >> 14;
    int rem0 = pix0 & 16383;
    const ushort_t* src = prebn + (size_t)pix0 * COUT;
#pragma unroll
    for (int r = 0; r < 32; ++r) {
        int i = r * 256 + t;
        int p = i >> 7, c = i & 127;
        float v = us2f(src[i]);
        v = fmaxf((v - mvs[c]) * mvs[128 + c], 0.0f);
        tile[c * 65 + p] = v;
    }
    __syncthreads();
#pragma unroll
    for (int r = 0; r < 32; ++r) {
        int i = r * 256 + t;
        int c2 = i >> 6, p2 = i & 63;
        out[(size_t)(b * COUT + c2) * HW + rem0 + p2] = tile[c2 * 65 + p2];
    }
}

// ---------------------------------------------------------------------------
extern "C" void kernel_launch(void* const* d_in, const int* in_sizes, int n_in,
                              void* d_out, int out_size, void* d_ws, size_t ws_size,
                              hipStream_t stream) {
    (void)in_sizes; (void)n_in; (void)out_size; (void)ws_size;
    const void* x     = d_in[0];
    const void* offw  = d_in[1];
    const void* offb  = d_in[2];
    const void* maskw = d_in[3];
    const void* maskb = d_in[4];
    const void* convw = d_in[5];

    float* ws       = (float*)d_ws;
    float* off2     = ws;                      // 2,359,296 f32 (y,x interleaved)
    float* mask_ws  = off2 + 2359296;          // 1,179,648 f32
    float* bias     = mask_ws + 1179648;       //        32 f32
    float* gstat    = bias + 32;               //     4,096 f32
    float* mv       = gstat + 4096;            //       256 f32
    float* flag     = mv + 256;                //        16 f32
    ushort_t* wTs   = (ushort_t*)(flag + 16);  //    73,728 bf16 (frag-linear)
    ushort_t* wcats = wTs + 73728;             //    18,432 bf16 (frag-linear)
    ushort_t* xnb   = wcats + 18432;           // 8,388,608 bf16 (NHWC x)
    ushort_t* prebn = xnb + 8388608;           // 16,777,216 bf16 (NHWC pre-BN)
    float* out      = (float*)d_out;

    hipMemsetAsync(gstat, 0, 4096 * sizeof(float), stream);
    detect_dtype<<<1, 1, 0, stream>>>((const unsigned short*)x, flag);
    prep_weights<true><<<361, 256, 0, stream>>>(offw, offb, maskw, maskb, convw, flag, wTs, wcats, bias);
    prep_weights<false><<<361, 256, 0, stream>>>(offw, offb, maskw, maskb, convw, flag, wTs, wcats, bias);
    transpose_x<true><<<2048, 256, 0, stream>>>(x, flag, xnb);
    transpose_x<false><<<2048, 256, 0, stream>>>(x, flag, xnb);
    conv_mfma<<<1024, 512, 0, stream>>>(xnb, wcats, bias, off2, mask_ws);
    deform_mfma<<<1024, 512, 0, stream>>>(xnb, off2, mask_ws, wTs, prebn, gstat);
    bn_stats<<<1, 128, 0, stream>>>(gstat, mv);
    bn_apply_t<<<2048, 256, 0, stream>>>(prebn, mv, out);
}

// Round 7
// 225.739 us; speedup vs baseline: 1.8099x; 1.1804x over previous
//
#include <hip/hip_runtime.h>
#include <hip/hip_bf16.h>

// Problem constants
#define H_ 128
#define W_ 128
#define HW 16384          // H*W
#define CIN 64
#define COUT 128
#define KK9 9
#define BATCH 8
#define NPIX (BATCH * HW) // 131072
#define KDIM 576          // CIN*KK9

typedef short bf16x8 __attribute__((ext_vector_type(8)));
typedef float f32x4  __attribute__((ext_vector_type(4)));
typedef unsigned short ushort_t;

union U4B { uint4 u; bf16x8 v; };

__device__ __forceinline__ float us2f(unsigned short u) {
    unsigned int v = ((unsigned int)u) << 16;
    float f;
    __builtin_memcpy(&f, &v, 4);
    return f;
}
__device__ __forceinline__ float lo_f(unsigned int w) {
    unsigned int v = w << 16;
    float f;
    __builtin_memcpy(&f, &v, 4);
    return f;
}
__device__ __forceinline__ float hi_f(unsigned int w) {
    unsigned int v = w & 0xffff0000u;
    float f;
    __builtin_memcpy(&f, &v, 4);
    return f;
}
__device__ __forceinline__ unsigned short f2us_bf(float f) {
    __hip_bfloat16 h = __float2bfloat16(f);
    unsigned short u;
    __builtin_memcpy(&u, &h, 2);
    return u;
}
__device__ __forceinline__ unsigned int pack2(float a, float b) {
    return (unsigned int)f2us_bf(a) | ((unsigned int)f2us_bf(b) << 16);
}

template <bool F32>
__device__ __forceinline__ float ld_in(const void* p, long i) {
    if (F32) return ((const float*)p)[i];
    return us2f(((const unsigned short*)p)[i]);
}

// ---------------------------------------------------------------------------
// detect_zero: dtype probe (1 wave, vector loads, ballot) + zero gstat.
// ---------------------------------------------------------------------------
__global__ void detect_zero(const uint4* __restrict__ xr4,
                            float* __restrict__ flag,
                            float* __restrict__ gstat) {
    int t = threadIdx.x;   // 256
#pragma unroll
    for (int i = 0; i < 16; ++i) gstat[i * 256 + t] = 0.0f;
    if (t < 64) {
        uint4 v = xr4[t];
        unsigned int w[4] = {v.x, v.y, v.z, v.w};
        int big = 0;
#pragma unroll
        for (int q = 0; q < 4; ++q) {
            big += (((w[q] >> 7)  & 0xFF) >= 0xC0);
            big += (((w[q] >> 23) & 0xFF) >= 0xC0);
        }
        unsigned long long m = __ballot(big > 0);
        if (t == 0) flag[0] = m ? 1.0f : 0.0f;
    }
}

// ---------------------------------------------------------------------------
// prep_weights: weights in MFMA-fragment-linear order.
// wTs  [18 ks][8 n][64 lane][8 j] bf16 from conv_w[co][ci][kk]
// wcats[18 ks][2 n][64 lane][8 j] (rows 0..17 offset_w, 18..26 mask_w, rest 0)
// bias [32] f32
// ---------------------------------------------------------------------------
template <bool F32>
__global__ void prep_weights(const void* __restrict__ offw,
                             const void* __restrict__ offb,
                             const void* __restrict__ maskw,
                             const void* __restrict__ maskb,
                             const void* __restrict__ convw,
                             const float* __restrict__ flag,
                             ushort_t* __restrict__ wTs,
                             ushort_t* __restrict__ wcats,
                             float* __restrict__ bias) {
    if ((flag[0] != 0.0f) != F32) return;
    int i = blockIdx.x * 256 + threadIdx.x;
    if (i < 73728) {
        int j = i & 7, lane = (i >> 3) & 63, n = (i >> 9) & 7, ks = i >> 12;
        int co = n * 16 + (lane & 15);
        int k  = ks * 32 + ((lane >> 4) << 3) + j;
        int kk = k >> 6, ci = k & 63;
        wTs[i] = f2us_bf(ld_in<F32>(convw, (long)co * KDIM + ci * 9 + kk));
    } else if (i < 73728 + 18432) {
        int i2 = i - 73728;
        int j = i2 & 7, lane = (i2 >> 3) & 63, n = (i2 >> 9) & 1, ks = i2 >> 10;
        int co2 = n * 16 + (lane & 15);
        int k   = ks * 32 + ((lane >> 4) << 3) + j;
        int kk = k >> 6, ci = k & 63;
        float v = 0.0f;
        if (co2 < 18)      v = ld_in<F32>(offw,  (long)co2 * KDIM + ci * 9 + kk);
        else if (co2 < 27) v = ld_in<F32>(maskw, (long)(co2 - 18) * KDIM + ci * 9 + kk);
        wcats[i2] = f2us_bf(v);
    } else if (i < 73728 + 18432 + 32) {
        int j = i - 73728 - 18432;
        float v = 0.0f;
        if (j < 18)      v = ld_in<F32>(offb, j);
        else if (j < 27) v = ld_in<F32>(maskb, j - 18);
        bias[j] = v;
    }
}

// ---------------------------------------------------------------------------
// transpose_x: raw x NCHW -> NHWC bf16.
// ---------------------------------------------------------------------------
template <bool F32>
__global__ __launch_bounds__(256) void transpose_x(const void* __restrict__ x,
                                                   const float* __restrict__ flag,
                                                   ushort_t* __restrict__ xnb) {
    if ((flag[0] != 0.0f) != F32) return;
    __shared__ float tile[CIN][64 + 1];
    int blk  = blockIdx.x;
    int b    = blk >> 8;
    int pix0 = (blk & 255) * 64;
    int t    = threadIdx.x;
    int lane = t & 63;
    int grp  = t >> 6;
#pragma unroll
    for (int r = 0; r < 16; ++r) {
        int ci = r * 4 + grp;
        tile[ci][lane] = ld_in<F32>(x, (long)(b * CIN + ci) * HW + pix0 + lane);
    }
    __syncthreads();
#pragma unroll
    for (int r = 0; r < 16; ++r) {
        int px = r * 4 + grp;
        xnb[(size_t)(b * HW + pix0 + px) * CIN + lane] = f2us_bf(tile[lane][px]);
    }
}

// ---------------------------------------------------------------------------
// conv_mfma: implicit-GEMM 3x3 conv -> 27 ch. 1024 thr / 256 px / 16 waves.
// B staged once in LDS (37 KB); ONE barrier; per-tap-row loop, no inner sync.
// ---------------------------------------------------------------------------
__global__ __launch_bounds__(1024, 4) void conv_mfma(
        const ushort_t* __restrict__ xnb,
        const ushort_t* __restrict__ wcats,
        const float* __restrict__ bias,
        float* __restrict__ off2,
        float* __restrict__ mask_ws) {
    __shared__ uint4 ldsB4[2304];    // 36,864 B

    int t    = threadIdx.x;
    int pix0 = blockIdx.x * 256;
    int b    = pix0 >> 14;
    int rem0 = pix0 & 16383;

    const uint4* ws4 = (const uint4*)wcats;
#pragma unroll
    for (int i = t; i < 2304; i += 1024) ldsB4[i] = ws4[i];

    int wave = t >> 6, lane = t & 63, mrow = lane & 15, quad = lane >> 4;
    int px_l = wave * 16 + mrow;
    int remp = rem0 + px_l;
    int yp = remp >> 7, xp = remp & 127;
    const ushort_t* xb = xnb + (size_t)b * HW * CIN + quad * 8;
    __syncthreads();

    f32x4 acc[2];
    acc[0] = (f32x4){0.f, 0.f, 0.f, 0.f};
    acc[1] = (f32x4){0.f, 0.f, 0.f, 0.f};
    const ushort_t* ldsB = (const ushort_t*)ldsB4;

#pragma unroll 1
    for (int ty = 0; ty < 3; ++ty) {
        int yy = yp + ty - 1;
        bool oky = (yy >= 0) && (yy < H_);
#pragma unroll
        for (int tx = 0; tx < 3; ++tx) {
            int kk = ty * 3 + tx;
            int xq = xp + tx - 1;
            bool ok = oky && (xq >= 0) && (xq < W_);
            const ushort_t* src = xb + (size_t)(yy * W_ + xq) * CIN;
            U4B a0, a1;
            a0.u = ok ? *(const uint4*)src        : make_uint4(0, 0, 0, 0);
            a1.u = ok ? *(const uint4*)(src + 32) : make_uint4(0, 0, 0, 0);
#pragma unroll
            for (int half = 0; half < 2; ++half) {
                int ks = kk * 2 + half;
                U4B a = half ? a1 : a0;
#pragma unroll
                for (int n = 0; n < 2; ++n) {
                    bf16x8 bf = *(const bf16x8*)(ldsB + ((ks * 2 + n) * 64 + lane) * 8);
                    acc[n] = __builtin_amdgcn_mfma_f32_16x16x32_bf16(a.v, bf, acc[n], 0, 0, 0);
                }
            }
        }
    }

    // epilogue
#pragma unroll
    for (int n = 0; n < 2; ++n) {
        int co2 = n * 16 + mrow;
        if (co2 >= 27) continue;
        float bs = bias[co2];
#pragma unroll
        for (int r = 0; r < 4; ++r) {
            int px = wave * 16 + quad * 4 + r;
            float v = acc[n][r] + bs;
            if (co2 < 18) {
                off2[((size_t)(b * 9 + (co2 >> 1)) * HW + rem0 + px) * 2 + (co2 & 1)] = v;
            } else {
                mask_ws[(size_t)(b * 9 + (co2 - 18)) * HW + rem0 + px] =
                    1.0f / (1.0f + __expf(-v));
            }
        }
    }
}

// ---------------------------------------------------------------------------
// deform_mfma: fused bilinear sampling + GEMM. 1024 thr / 256 px / 16 waves.
// B = full W^T (147 KB fragment-linear) staged once; ONE barrier; then each
// wave independently loops tap-rows: {gather 3 taps -> interp -> 32 MFMAs}.
// Waves drift out of phase -> gather latency hidden by other waves' compute.
// Pre-BN output bf16 NHWC + per-channel BN stats.
// ---------------------------------------------------------------------------
__global__ __launch_bounds__(1024, 4) void deform_mfma(
        const ushort_t* __restrict__ xnb,
        const float* __restrict__ off2,
        const float* __restrict__ mask_ws,
        const ushort_t* __restrict__ wTs,
        ushort_t* __restrict__ prebn,
        float* __restrict__ gstat) {
    __shared__ uint4 ldsB4[9216];    // 147,456 B
    __shared__ float red[256];

    int t    = threadIdx.x;
    int pix0 = blockIdx.x * 256;
    int b    = pix0 >> 14;
    int rem0 = pix0 & 16383;

    const uint4* ws4 = (const uint4*)wTs;
#pragma unroll
    for (int i = 0; i < 9; ++i) ldsB4[i * 1024 + t] = ws4[i * 1024 + t];
    if (t < 256) red[t] = 0.0f;

    int wave = t >> 6, lane = t & 63, mrow = lane & 15, quad = lane >> 4;
    int px_l = wave * 16 + mrow;
    int remp = rem0 + px_l;
    int yp = remp >> 7, xp = remp & 127;
    const ushort_t* xb = xnb + (size_t)b * HW * CIN + quad * 8;
    size_t obase = (size_t)b * 9 * HW + remp;
    __syncthreads();

    f32x4 acc[8];
#pragma unroll
    for (int n = 0; n < 8; ++n) acc[n] = (f32x4){0.f, 0.f, 0.f, 0.f};
    const ushort_t* ldsB = (const ushort_t*)ldsB4;

#pragma unroll 1
    for (int ty = 0; ty < 3; ++ty) {
        // offsets+mask for this tap row (3 taps, independent loads)
        float oy[3], ox[3], m3[3];
#pragma unroll
        for (int tx = 0; tx < 3; ++tx) {
            int kk = ty * 3 + tx;
            float2 o = *(const float2*)(off2 + (obase + (size_t)kk * HW) * 2);
            oy[tx] = o.x; ox[tx] = o.y;
            m3[tx] = mask_ws[obase + (size_t)kk * HW];
        }
#pragma unroll
        for (int tx = 0; tx < 3; ++tx) {
            int kk = ty * 3 + tx;
            float py  = (float)(yp + ty - 1) + oy[tx];
            float pxf = (float)(xp + tx - 1) + ox[tx];
            float y0f = floorf(py), x0f = floorf(pxf);
            int yi = (int)y0f, xi = (int)x0f;
            float wy1 = py - y0f, wx1 = pxf - x0f;
            float wy0 = 1.0f - wy1, wx0 = 1.0f - wx1;
            float v[16];
#pragma unroll
            for (int j = 0; j < 16; ++j) v[j] = 0.0f;
#pragma unroll
            for (int c = 0; c < 4; ++c) {
                int ys = yi + (c >> 1);
                int xs = xi + (c & 1);
                float wgt = ((c >> 1) ? wy1 : wy0) * ((c & 1) ? wx1 : wx0);
                if (ys >= 0 && ys < H_ && xs >= 0 && xs < W_) {
                    const ushort_t* src = xb + (size_t)(ys * W_ + xs) * CIN;
                    uint4 l4 = *(const uint4*)src;          // ci quad*8..+8
                    uint4 h4 = *(const uint4*)(src + 32);   // ci 32+quad*8..+8
                    unsigned int ww[8] = {l4.x, l4.y, l4.z, l4.w,
                                          h4.x, h4.y, h4.z, h4.w};
#pragma unroll
                    for (int j = 0; j < 8; ++j) {
                        v[2 * j]     = fmaf(wgt, lo_f(ww[j]), v[2 * j]);
                        v[2 * j + 1] = fmaf(wgt, hi_f(ww[j]), v[2 * j + 1]);
                    }
                }
            }
            float m = m3[tx];
            unsigned int w[8];
#pragma unroll
            for (int j = 0; j < 8; ++j)
                w[j] = pack2(v[2 * j] * m, v[2 * j + 1] * m);
            U4B a0, a1;
            a0.u = make_uint4(w[0], w[1], w[2], w[3]);
            a1.u = make_uint4(w[4], w[5], w[6], w[7]);
#pragma unroll
            for (int half = 0; half < 2; ++half) {
                int ks = kk * 2 + half;
                U4B a = half ? a1 : a0;
                const ushort_t* bbase = ldsB + ((size_t)(ks * 8) * 64 + lane) * 8;
#pragma unroll
                for (int n = 0; n < 8; ++n) {
                    bf16x8 bf = *(const bf16x8*)(bbase + n * 64 * 8);
                    acc[n] = __builtin_amdgcn_mfma_f32_16x16x32_bf16(a.v, bf, acc[n], 0, 0, 0);
                }
            }
        }
    }

    // ---- epilogue: bf16 NHWC store + BN stats (shuffle-reduce) ----
#pragma unroll
    for (int n = 0; n < 8; ++n) {
        int co = n * 16 + mrow;
        float s = 0.f, ss = 0.f;
#pragma unroll
        for (int r = 0; r < 4; ++r) {
            int pg = pix0 + wave * 16 + quad * 4 + r;
            float v = acc[n][r];
            prebn[(size_t)pg * COUT + co] = f2us_bf(v);
            s += v;
            ss += v * v;
        }
        s  += __shfl_xor(s, 16, 64);
        s  += __shfl_xor(s, 32, 64);
        ss += __shfl_xor(ss, 16, 64);
        ss += __shfl_xor(ss, 32, 64);
        if (quad == 0) {
            atomicAdd(&red[co], s);
            atomicAdd(&red[128 + co], ss);
        }
    }
    __syncthreads();
    if (t < 256) atomicAdd(&gstat[(blockIdx.x & 15) * 256 + t], red[t]);
}

// ---------------------------------------------------------------------------
// bn_apply_t: derive mean/rstd from gstat per block (cheap), then read pre-BN
// bf16 NHWC, normalize+ReLU, write f32 NCHW d_out via LDS transpose tile.
// ---------------------------------------------------------------------------
__global__ __launch_bounds__(256) void bn_apply_t(const ushort_t* __restrict__ prebn,
                                                  const float* __restrict__ gstat,
                                                  float* __restrict__ out) {
    __shared__ float tile[128 * 65];
    __shared__ float mvs[256];
    int t = threadIdx.x;
    if (t < 128) {
        float s = 0.f, ss = 0.f;
#pragma unroll
        for (int part = 0; part < 16; ++part) {
            s  += gstat[part * 256 + t];
            ss += gstat[part * 256 + 128 + t];
        }
        const float invN = 1.0f / (float)NPIX;
        float mean = s * invN;
        float var  = ss * invN - mean * mean;
        if (!isfinite(mean)) mean = 0.0f;
        float r = rsqrtf(fmaxf(var, 0.0f) + 1e-5f);
        if (!isfinite(r)) r = 1.0f;
        mvs[t]       = mean;
        mvs[128 + t] = r;
    }
    __syncthreads();
    int pix0 = blockIdx.x * 64;
    int b    = pix0 >> 14;
    int rem0 = pix0 & 16383;
    const ushort_t* src = prebn + (size_t)pix0 * COUT;
#pragma unroll
    for (int r = 0; r < 32; ++r) {
        int i = r * 256 + t;
        int p = i >> 7, c = i & 127;
        float v = us2f(src[i]);
        v = fmaxf((v - mvs[c]) * mvs[128 + c], 0.0f);
        tile[c * 65 + p] = v;
    }
    __syncthreads();
#pragma unroll
    for (int r = 0; r < 32; ++r) {
        int i = r * 256 + t;
        int c2 = i >> 6, p2 = i & 63;
        out[(size_t)(b * COUT + c2) * HW + rem0 + p2] = tile[c2 * 65 + p2];
    }
}

// ---------------------------------------------------------------------------
extern "C" void kernel_launch(void* const* d_in, const int* in_sizes, int n_in,
                              void* d_out, int out_size, void* d_ws, size_t ws_size,
                              hipStream_t stream) {
    (void)in_sizes; (void)n_in; (void)out_size; (void)ws_size;
    const void* x     = d_in[0];
    const void* offw  = d_in[1];
    const void* offb  = d_in[2];
    const void* maskw = d_in[3];
    const void* maskb = d_in[4];
    const void* convw = d_in[5];

    float* ws       = (float*)d_ws;
    float* off2     = ws;                      // 2,359,296 f32 (y,x interleaved)
    float* mask_ws  = off2 + 2359296;          // 1,179,648 f32
    float* bias     = mask_ws + 1179648;       //        32 f32
    float* gstat    = bias + 32;               //     4,096 f32
    float* flag     = gstat + 4096;            //        16 f32
    ushort_t* wTs   = (ushort_t*)(flag + 16);  //    73,728 bf16 (frag-linear)
    ushort_t* wcats = wTs + 73728;             //    18,432 bf16 (frag-linear)
    ushort_t* xnb   = wcats + 18432;           // 8,388,608 bf16 (NHWC x)
    ushort_t* prebn = xnb + 8388608;           // 16,777,216 bf16 (NHWC pre-BN)
    float* out      = (float*)d_out;

    detect_zero<<<1, 256, 0, stream>>>((const uint4*)x, flag, gstat);
    prep_weights<true><<<361, 256, 0, stream>>>(offw, offb, maskw, maskb, convw, flag, wTs, wcats, bias);
    prep_weights<false><<<361, 256, 0, stream>>>(offw, offb, maskw, maskb, convw, flag, wTs, wcats, bias);
    transpose_x<true><<<2048, 256, 0, stream>>>(x, flag, xnb);
    transpose_x<false><<<2048, 256, 0, stream>>>(x, flag, xnb);
    conv_mfma<<<512, 1024, 0, stream>>>(xnb, wcats, bias, off2, mask_ws);
    deform_mfma<<<512, 1024, 0, stream>>>(xnb, off2, mask_ws, wTs, prebn, gstat);
    bn_apply_t<<<2048, 256, 0, stream>>>(prebn, gstat, out);
}

// Round 8
// 223.840 us; speedup vs baseline: 1.8252x; 1.0085x over previous
//
#include <hip/hip_runtime.h>
#include <hip/hip_bf16.h>

// Problem constants
#define H_ 128
#define W_ 128
#define HW 16384          // H*W
#define CIN 64
#define COUT 128
#define KK9 9
#define BATCH 8
#define NPIX (BATCH * HW) // 131072
#define KDIM 576          // CIN*KK9

typedef short bf16x8 __attribute__((ext_vector_type(8)));
typedef float f32x4  __attribute__((ext_vector_type(4)));
typedef unsigned short ushort_t;

union U4B { uint4 u; bf16x8 v; };

__device__ __forceinline__ float us2f(unsigned short u) {
    unsigned int v = ((unsigned int)u) << 16;
    float f;
    __builtin_memcpy(&f, &v, 4);
    return f;
}
__device__ __forceinline__ float lo_f(unsigned int w) {
    unsigned int v = w << 16;
    float f;
    __builtin_memcpy(&f, &v, 4);
    return f;
}
__device__ __forceinline__ float hi_f(unsigned int w) {
    unsigned int v = w & 0xffff0000u;
    float f;
    __builtin_memcpy(&f, &v, 4);
    return f;
}
__device__ __forceinline__ unsigned short f2us_bf(float f) {
    __hip_bfloat16 h = __float2bfloat16(f);
    unsigned short u;
    __builtin_memcpy(&u, &h, 2);
    return u;
}
__device__ __forceinline__ unsigned int pack2(float a, float b) {
    return (unsigned int)f2us_bf(a) | ((unsigned int)f2us_bf(b) << 16);
}

template <bool F32>
__device__ __forceinline__ float ld_in(const void* p, long i) {
    if (F32) return ((const float*)p)[i];
    return us2f(((const unsigned short*)p)[i]);
}

// ---------------------------------------------------------------------------
// detect_zero: dtype probe (1 wave, vector loads, ballot) + zero gstat.
// ---------------------------------------------------------------------------
__global__ void detect_zero(const uint4* __restrict__ xr4,
                            float* __restrict__ flag,
                            float* __restrict__ gstat) {
    int t = threadIdx.x;   // 256
#pragma unroll
    for (int i = 0; i < 16; ++i) gstat[i * 256 + t] = 0.0f;
    if (t < 64) {
        uint4 v = xr4[t];
        unsigned int w[4] = {v.x, v.y, v.z, v.w};
        int big = 0;
#pragma unroll
        for (int q = 0; q < 4; ++q) {
            big += (((w[q] >> 7)  & 0xFF) >= 0xC0);
            big += (((w[q] >> 23) & 0xFF) >= 0xC0);
        }
        unsigned long long m = __ballot(big > 0);
        if (t == 0) flag[0] = m ? 1.0f : 0.0f;
    }
}

// ---------------------------------------------------------------------------
// prep_weights: weights in MFMA-fragment-linear order. Single kernel,
// internal wave-uniform branch on flag.
// wTs  [18 ks][8 n][64 lane][8 j] bf16 from conv_w[co][ci][kk]
// wcats[18 ks][2 n][64 lane][8 j] (rows 0..17 offset_w, 18..26 mask_w, rest 0)
// bias [32] f32
// ---------------------------------------------------------------------------
template <bool F32>
__device__ __forceinline__ void prep_body(const void* offw, const void* offb,
                                          const void* maskw, const void* maskb,
                                          const void* convw,
                                          ushort_t* wTs, ushort_t* wcats,
                                          float* bias, int i) {
    if (i < 73728) {
        int j = i & 7, lane = (i >> 3) & 63, n = (i >> 9) & 7, ks = i >> 12;
        int co = n * 16 + (lane & 15);
        int k  = ks * 32 + ((lane >> 4) << 3) + j;
        int kk = k >> 6, ci = k & 63;
        wTs[i] = f2us_bf(ld_in<F32>(convw, (long)co * KDIM + ci * 9 + kk));
    } else if (i < 73728 + 18432) {
        int i2 = i - 73728;
        int j = i2 & 7, lane = (i2 >> 3) & 63, n = (i2 >> 9) & 1, ks = i2 >> 10;
        int co2 = n * 16 + (lane & 15);
        int k   = ks * 32 + ((lane >> 4) << 3) + j;
        int kk = k >> 6, ci = k & 63;
        float v = 0.0f;
        if (co2 < 18)      v = ld_in<F32>(offw,  (long)co2 * KDIM + ci * 9 + kk);
        else if (co2 < 27) v = ld_in<F32>(maskw, (long)(co2 - 18) * KDIM + ci * 9 + kk);
        wcats[i2] = f2us_bf(v);
    } else if (i < 73728 + 18432 + 32) {
        int j = i - 73728 - 18432;
        float v = 0.0f;
        if (j < 18)      v = ld_in<F32>(offb, j);
        else if (j < 27) v = ld_in<F32>(maskb, j - 18);
        bias[j] = v;
    }
}

__global__ void prep_weights(const void* __restrict__ offw,
                             const void* __restrict__ offb,
                             const void* __restrict__ maskw,
                             const void* __restrict__ maskb,
                             const void* __restrict__ convw,
                             const float* __restrict__ flag,
                             ushort_t* __restrict__ wTs,
                             ushort_t* __restrict__ wcats,
                             float* __restrict__ bias) {
    int i = blockIdx.x * 256 + threadIdx.x;
    if (flag[0] != 0.0f)
        prep_body<true>(offw, offb, maskw, maskb, convw, wTs, wcats, bias, i);
    else
        prep_body<false>(offw, offb, maskw, maskb, convw, wTs, wcats, bias, i);
}

// ---------------------------------------------------------------------------
// transpose_x: raw x NCHW -> NHWC bf16. Single kernel, internal flag branch.
// ---------------------------------------------------------------------------
template <bool F32>
__device__ __forceinline__ void transpose_body(const void* x, ushort_t* xnb) {
    __shared__ float tile[CIN][64 + 1];
    int blk  = blockIdx.x;
    int b    = blk >> 8;
    int pix0 = (blk & 255) * 64;
    int t    = threadIdx.x;
    int lane = t & 63;
    int grp  = t >> 6;
#pragma unroll
    for (int r = 0; r < 16; ++r) {
        int ci = r * 4 + grp;
        tile[ci][lane] = ld_in<F32>(x, (long)(b * CIN + ci) * HW + pix0 + lane);
    }
    __syncthreads();
#pragma unroll
    for (int r = 0; r < 16; ++r) {
        int px = r * 4 + grp;
        xnb[(size_t)(b * HW + pix0 + px) * CIN + lane] = f2us_bf(tile[lane][px]);
    }
}

__global__ __launch_bounds__(256) void transpose_x(const void* __restrict__ x,
                                                   const float* __restrict__ flag,
                                                   ushort_t* __restrict__ xnb) {
    if (flag[0] != 0.0f) transpose_body<true>(x, xnb);
    else                 transpose_body<false>(x, xnb);
}

// ---------------------------------------------------------------------------
// conv_mfma: implicit-GEMM 3x3 conv -> 27 ch. 1024 thr / 256 px / 16 waves.
// All 9 taps preloaded into registers (coalesced, deep MLP); B in LDS; ONE
// barrier; then pure MFMA+ds_read loop.
// ---------------------------------------------------------------------------
__global__ __launch_bounds__(1024, 4) void conv_mfma(
        const ushort_t* __restrict__ xnb,
        const ushort_t* __restrict__ wcats,
        const float* __restrict__ bias,
        float* __restrict__ off2,
        float* __restrict__ mask_ws) {
    __shared__ uint4 ldsB4[2304];    // 36,864 B

    int t    = threadIdx.x;
    int pix0 = blockIdx.x * 256;
    int b    = pix0 >> 14;
    int rem0 = pix0 & 16383;

    const uint4* ws4 = (const uint4*)wcats;
#pragma unroll
    for (int i = t; i < 2304; i += 1024) ldsB4[i] = ws4[i];

    int wave = t >> 6, lane = t & 63, mrow = lane & 15, quad = lane >> 4;
    int px_l = wave * 16 + mrow;
    int remp = rem0 + px_l;
    int yp = remp >> 7, xp = remp & 127;
    const ushort_t* xb = xnb + (size_t)b * HW * CIN + quad * 8;

    // preload all 9 taps (loads all independent)
    uint4 af0[9], af1[9];
#pragma unroll
    for (int kk = 0; kk < 9; ++kk) {
        int yy = yp + kk / 3 - 1;
        int xq = xp + kk % 3 - 1;
        bool ok = (yy >= 0) && (yy < H_) && (xq >= 0) && (xq < W_);
        const ushort_t* src = xb + (size_t)(yy * W_ + xq) * CIN;
        af0[kk] = ok ? *(const uint4*)src        : make_uint4(0, 0, 0, 0);
        af1[kk] = ok ? *(const uint4*)(src + 32) : make_uint4(0, 0, 0, 0);
    }
    __syncthreads();

    f32x4 acc[2];
    acc[0] = (f32x4){0.f, 0.f, 0.f, 0.f};
    acc[1] = (f32x4){0.f, 0.f, 0.f, 0.f};
    const ushort_t* ldsB = (const ushort_t*)ldsB4;
#pragma unroll
    for (int kk = 0; kk < 9; ++kk) {
#pragma unroll
        for (int half = 0; half < 2; ++half) {
            int ks = kk * 2 + half;
            U4B a; a.u = half ? af1[kk] : af0[kk];
#pragma unroll
            for (int n = 0; n < 2; ++n) {
                bf16x8 bf = *(const bf16x8*)(ldsB + ((ks * 2 + n) * 64 + lane) * 8);
                acc[n] = __builtin_amdgcn_mfma_f32_16x16x32_bf16(a.v, bf, acc[n], 0, 0, 0);
            }
        }
    }

    // epilogue
#pragma unroll
    for (int n = 0; n < 2; ++n) {
        int co2 = n * 16 + mrow;
        if (co2 >= 27) continue;
        float bs = bias[co2];
#pragma unroll
        for (int r = 0; r < 4; ++r) {
            int px = wave * 16 + quad * 4 + r;
            float v = acc[n][r] + bs;
            if (co2 < 18) {
                off2[((size_t)(b * 9 + (co2 >> 1)) * HW + rem0 + px) * 2 + (co2 & 1)] = v;
            } else {
                mask_ws[(size_t)(b * 9 + (co2 - 18)) * HW + rem0 + px] =
                    1.0f / (1.0f + __expf(-v));
            }
        }
    }
}

// ---------------------------------------------------------------------------
// deform_mfma helpers: issue (addresses+loads, clamped, no divergence) and
// consume (interp + pack + 16 MFMAs) for one tap.
// ---------------------------------------------------------------------------
__device__ __forceinline__ void issue_tap(int kk, int yp, int xp,
                                          float oy, float ox,
                                          const ushort_t* __restrict__ xb,
                                          uint4* cb, float* wg) {
    int ty = kk / 3, tx = kk % 3;
    float py  = (float)(yp + ty - 1) + oy;
    float pxf = (float)(xp + tx - 1) + ox;
    float y0f = floorf(py), x0f = floorf(pxf);
    int yi = (int)y0f, xi = (int)x0f;
    float wy1 = py - y0f, wx1 = pxf - x0f;
    float wy0 = 1.0f - wy1, wx0 = 1.0f - wx1;
#pragma unroll
    for (int c = 0; c < 4; ++c) {
        int dy = c >> 1, dx = c & 1;
        int ys = yi + dy, xs = xi + dx;
        bool ok = (ys >= 0) && (ys < H_) && (xs >= 0) && (xs < W_);
        int ysc = min(max(ys, 0), H_ - 1);
        int xsc = min(max(xs, 0), W_ - 1);
        float w = (dy ? wy1 : wy0) * (dx ? wx1 : wx0);
        wg[c] = ok ? w : 0.0f;
        const ushort_t* src = xb + (size_t)(ysc * W_ + xsc) * CIN;
        cb[2 * c]     = *(const uint4*)src;
        cb[2 * c + 1] = *(const uint4*)(src + 32);
    }
}

__device__ __forceinline__ void consume_tap(int kk, const uint4* cb,
                                            const float* wg, float mk,
                                            const ushort_t* __restrict__ ldsB,
                                            int lane, f32x4* acc) {
    float2 v2[8];
#pragma unroll
    for (int j = 0; j < 8; ++j) v2[j] = make_float2(0.f, 0.f);
#pragma unroll
    for (int c = 0; c < 4; ++c) {
        float w = wg[c];
        unsigned int ww[8] = {cb[2 * c].x,     cb[2 * c].y,
                              cb[2 * c].z,     cb[2 * c].w,
                              cb[2 * c + 1].x, cb[2 * c + 1].y,
                              cb[2 * c + 1].z, cb[2 * c + 1].w};
#pragma unroll
        for (int j = 0; j < 8; ++j) {
            v2[j].x = fmaf(w, lo_f(ww[j]), v2[j].x);
            v2[j].y = fmaf(w, hi_f(ww[j]), v2[j].y);
        }
    }
    unsigned int w8[8];
#pragma unroll
    for (int j = 0; j < 8; ++j)
        w8[j] = pack2(v2[j].x * mk, v2[j].y * mk);
    U4B a0, a1;
    a0.u = make_uint4(w8[0], w8[1], w8[2], w8[3]);
    a1.u = make_uint4(w8[4], w8[5], w8[6], w8[7]);
#pragma unroll
    for (int half = 0; half < 2; ++half) {
        int ks = kk * 2 + half;
        U4B a = half ? a1 : a0;
        const ushort_t* bbase = ldsB + ((size_t)(ks * 8) * 64 + lane) * 8;
#pragma unroll
        for (int n = 0; n < 8; ++n) {
            bf16x8 bf = *(const bf16x8*)(bbase + n * 64 * 8);
            acc[n] = __builtin_amdgcn_mfma_f32_16x16x32_bf16(a.v, bf, acc[n], 0, 0, 0);
        }
    }
}

// ---------------------------------------------------------------------------
// deform_mfma: fused bilinear sampling + GEMM. 1024 thr / 256 px / 16 waves.
// B = full W^T (147 KB fragment-linear) staged once; ONE barrier; then each
// wave runs a SOFTWARE-PIPELINED tap loop: issue tap k+1's 8 corner loads
// before consuming tap k (interp + 16 MFMAs) -> gather latency hidden.
// Pre-BN output bf16 NHWC + per-channel BN stats.
// ---------------------------------------------------------------------------
__global__ __launch_bounds__(1024, 4) void deform_mfma(
        const ushort_t* __restrict__ xnb,
        const float* __restrict__ off2,
        const float* __restrict__ mask_ws,
        const ushort_t* __restrict__ wTs,
        ushort_t* __restrict__ prebn,
        float* __restrict__ gstat) {
    __shared__ uint4 ldsB4[9216];    // 147,456 B
    __shared__ float red[256];

    int t    = threadIdx.x;
    int pix0 = blockIdx.x * 256;
    int b    = pix0 >> 14;
    int rem0 = pix0 & 16383;

    const uint4* ws4 = (const uint4*)wTs;
#pragma unroll
    for (int i = 0; i < 9; ++i) ldsB4[i * 1024 + t] = ws4[i * 1024 + t];
    if (t < 256) red[t] = 0.0f;

    int wave = t >> 6, lane = t & 63, mrow = lane & 15, quad = lane >> 4;
    int px_l = wave * 16 + mrow;
    int remp = rem0 + px_l;
    int yp = remp >> 7, xp = remp & 127;
    const ushort_t* xb = xnb + (size_t)b * HW * CIN + quad * 8;
    size_t obase = (size_t)b * 9 * HW + remp;

    // prefetch all offsets + masks (independent loads, issued upfront)
    float oyv[9], oxv[9], mkv[9];
#pragma unroll
    for (int kk = 0; kk < 9; ++kk) {
        float2 o = *(const float2*)(off2 + (obase + (size_t)kk * HW) * 2);
        oyv[kk] = o.x; oxv[kk] = o.y;
        mkv[kk] = mask_ws[obase + (size_t)kk * HW];
    }
    __syncthreads();

    f32x4 acc[8];
#pragma unroll
    for (int n = 0; n < 8; ++n) acc[n] = (f32x4){0.f, 0.f, 0.f, 0.f};
    const ushort_t* ldsB = (const ushort_t*)ldsB4;

    // software-pipelined tap loop (lookahead 1)
    uint4 cb0[8], cb1[8];
    float wg0[4], wg1[4];
    issue_tap(0, yp, xp, oyv[0], oxv[0], xb, cb0, wg0);
#pragma unroll
    for (int kk = 0; kk < 9; ++kk) {
        if (kk & 1) {
            if (kk < 8) issue_tap(kk + 1, yp, xp, oyv[kk + 1], oxv[kk + 1], xb, cb0, wg0);
            consume_tap(kk, cb1, wg1, mkv[kk], ldsB, lane, acc);
        } else {
            if (kk < 8) issue_tap(kk + 1, yp, xp, oyv[kk + 1], oxv[kk + 1], xb, cb1, wg1);
            consume_tap(kk, cb0, wg0, mkv[kk], ldsB, lane, acc);
        }
    }

    // ---- epilogue: bf16 NHWC store + BN stats (shuffle-reduce) ----
#pragma unroll
    for (int n = 0; n < 8; ++n) {
        int co = n * 16 + mrow;
        float s = 0.f, ss = 0.f;
#pragma unroll
        for (int r = 0; r < 4; ++r) {
            int pg = pix0 + wave * 16 + quad * 4 + r;
            float v = acc[n][r];
            prebn[(size_t)pg * COUT + co] = f2us_bf(v);
            s += v;
            ss += v * v;
        }
        s  += __shfl_xor(s, 16, 64);
        s  += __shfl_xor(s, 32, 64);
        ss += __shfl_xor(ss, 16, 64);
        ss += __shfl_xor(ss, 32, 64);
        if (quad == 0) {
            atomicAdd(&red[co], s);
            atomicAdd(&red[128 + co], ss);
        }
    }
    __syncthreads();
    if (t < 256) atomicAdd(&gstat[(blockIdx.x & 15) * 256 + t], red[t]);
}

// ---------------------------------------------------------------------------
// bn_apply_t: derive mean/rstd from gstat per block (cheap), then read pre-BN
// bf16 NHWC, normalize+ReLU, write f32 NCHW d_out via LDS transpose tile.
// ---------------------------------------------------------------------------
__global__ __launch_bounds__(256) void bn_apply_t(const ushort_t* __restrict__ prebn,
                                                  const float* __restrict__ gstat,
                                                  float* __restrict__ out) {
    __shared__ float tile[128 * 65];
    __shared__ float mvs[256];
    int t = threadIdx.x;
    if (t < 128) {
        float s = 0.f, ss = 0.f;
#pragma unroll
        for (int part = 0; part < 16; ++part) {
            s  += gstat[part * 256 + t];
            ss += gstat[part * 256 + 128 + t];
        }
        const float invN = 1.0f / (float)NPIX;
        float mean = s * invN;
        float var  = ss * invN - mean * mean;
        if (!isfinite(mean)) mean = 0.0f;
        float r = rsqrtf(fmaxf(var, 0.0f) + 1e-5f);
        if (!isfinite(r)) r = 1.0f;
        mvs[t]       = mean;
        mvs[128 + t] = r;
    }
    __syncthreads();
    int pix0 = blockIdx.x * 64;
    int b    = pix0 >> 14;
    int rem0 = pix0 & 16383;
    const ushort_t* src = prebn + (size_t)pix0 * COUT;
#pragma unroll
    for (int r = 0; r < 32; ++r) {
        int i = r * 256 + t;
        int p = i >> 7, c = i & 127;
        float v = us2f(src[i]);
        v = fmaxf((v - mvs[c]) * mvs[128 + c], 0.0f);
        tile[c * 65 + p] = v;
    }
    __syncthreads();
#pragma unroll
    for (int r = 0; r < 32; ++r) {
        int i = r * 256 + t;
        int c2 = i >> 6, p2 = i & 63;
        out[(size_t)(b * COUT + c2) * HW + rem0 + p2] = tile[c2 * 65 + p2];
    }
}

// ---------------------------------------------------------------------------
extern "C" void kernel_launch(void* const* d_in, const int* in_sizes, int n_in,
                              void* d_out, int out_size, void* d_ws, size_t ws_size,
                              hipStream_t stream) {
    (void)in_sizes; (void)n_in; (void)out_size; (void)ws_size;
    const void* x     = d_in[0];
    const void* offw  = d_in[1];
    const void* offb  = d_in[2];
    const void* maskw = d_in[3];
    const void* maskb = d_in[4];
    const void* convw = d_in[5];

    float* ws       = (float*)d_ws;
    float* off2     = ws;                      // 2,359,296 f32 (y,x interleaved)
    float* mask_ws  = off2 + 2359296;          // 1,179,648 f32
    float* bias     = mask_ws + 1179648;       //        32 f32
    float* gstat    = bias + 32;               //     4,096 f32
    float* flag     = gstat + 4096;            //        16 f32
    ushort_t* wTs   = (ushort_t*)(flag + 16);  //    73,728 bf16 (frag-linear)
    ushort_t* wcats = wTs + 73728;             //    18,432 bf16 (frag-linear)
    ushort_t* xnb   = wcats + 18432;           // 8,388,608 bf16 (NHWC x)
    ushort_t* prebn = xnb + 8388608;           // 16,777,216 bf16 (NHWC pre-BN)
    float* out      = (float*)d_out;

    detect_zero<<<1, 256, 0, stream>>>((const uint4*)x, flag, gstat);
    prep_weights<<<361, 256, 0, stream>>>(offw, offb, maskw, maskb, convw, flag, wTs, wcats, bias);
    transpose_x<<<2048, 256, 0, stream>>>(x, flag, xnb);
    conv_mfma<<<512, 1024, 0, stream>>>(xnb, wcats, bias, off2, mask_ws);
    deform_mfma<<<512, 1024, 0, stream>>>(xnb, off2, mask_ws, wTs, prebn, gstat);
    bn_apply_t<<<2048, 256, 0, stream>>>(prebn, gstat, out);
}